// Round 5
// baseline (186.680 us; speedup 1.0000x reference)
//
#include <hip/hip_runtime.h>

// Gaussian-kernel MMD loss, N=M=8192, D=2 — prep kernel + dynamically
// scheduled pairwise kernel.
// loss = mean(k_bb) + mean(k_tt) - 2*mean(k_bt), k = exp(-||x-y||^2/(2 s^2))
// - Centering affects only the cross term: shift folded into A (base) side.
// - Coords pre-scaled by exp(log_scale)*sqrt(inv2s2*log2e); dot-form exponent
//   e = fma(2ax,bx,-|b|^2) + fma(2ay,by,-|a|^2); k = exp2(e).
// - 4160 tiles of 128x256: 2048 cross + 2x1056 symmetric upper-triangle
//   (off-diag weight 2, diagonal-band tiles per-pair masked).
// - Dynamic balance: blocks grab tiles via atomicAdd work counter (prep zeroes
//   it). Done-counter: last block reads the f64 accumulator and writes out.
// - Exp-skip: sigma=0.1 => ~99.9% of pairs have e < -40 (k < 2^-40, aggregate
//   dropped mass ~1e-10 << 4.7e-6 threshold). Wave-uniform branch skips exp2.

#define BLOCK    256
#define GRID     2048
#define NT_CROSS 2048          // 64 x 32 tiles (128 rows x 256 cols)
#define NT_SYM   2112          // 2 terms x 1056 upper-triangle tiles
#define NT_TOT   (NT_CROSS + NT_SYM)
#define LOG2E    1.4426950408889634f
#define SKIP_CUT (-40.0f)

struct Prep { float f0, f1, sh0, sh1; };

__device__ __forceinline__ float fexp2(float x) {
    return __builtin_amdgcn_exp2f(x);
}

// ---------------- prep: means, constants, counter init ----------------
__global__ __launch_bounds__(1024) void prep_kernel(
    const float* __restrict__ base, const float* __restrict__ target,
    const float* __restrict__ log_sigma, const float* __restrict__ log_scale,
    int N, int M, Prep* __restrict__ pp,
    unsigned* __restrict__ wctr, unsigned* __restrict__ dctr,
    double* __restrict__ acc)
{
    __shared__ double mred[16][4];
    const int tid = threadIdx.x;
    if (tid == 0) { *wctr = 0u; *dctr = 0u; *acc = 0.0; }

    double sbx = 0, sby = 0, stx = 0, sty = 0;
    const float4* b4 = (const float4*)base;
    const float4* t4 = (const float4*)target;
    for (int i = tid; i < (N >> 1); i += 1024) {
        float4 v = b4[i];
        sbx += (double)v.x + (double)v.z;
        sby += (double)v.y + (double)v.w;
    }
    for (int i = tid; i < (M >> 1); i += 1024) {
        float4 v = t4[i];
        stx += (double)v.x + (double)v.z;
        sty += (double)v.y + (double)v.w;
    }
    for (int off = 32; off; off >>= 1) {
        sbx += __shfl_down(sbx, off); sby += __shfl_down(sby, off);
        stx += __shfl_down(stx, off); sty += __shfl_down(sty, off);
    }
    if ((tid & 63) == 0) {
        mred[tid >> 6][0] = sbx; mred[tid >> 6][1] = sby;
        mred[tid >> 6][2] = stx; mred[tid >> 6][3] = sty;
    }
    __syncthreads();
    if (tid == 0) {
        double b0 = 0, b1 = 0, t0 = 0, t1 = 0;
        for (int k = 0; k < 16; ++k) {
            b0 += mred[k][0]; b1 += mred[k][1];
            t0 += mred[k][2]; t1 += mred[k][3];
        }
        float s0 = expf(log_scale[0]);
        float s1 = expf(log_scale[1]);
        float sigma = expf(log_sigma[0]);
        float inv2s2 = 1.0f / (2.0f * sigma * sigma);
        float sq = sqrtf(inv2s2 * LOG2E);
        float f0 = s0 * sq, f1 = s1 * sq;
        pp->f0 = f0; pp->f1 = f1;
        pp->sh0 = (float)(b0 / (double)N - t0 / (double)M) * f0;
        pp->sh1 = (float)(b1 / (double)N - t1 / (double)M) * f1;
    }
}

// ---------------- main: dynamically scheduled 128x256 tiles ----------------
__global__ __launch_bounds__(BLOCK, 8) void mmd_main(
    const float* __restrict__ base, const float* __restrict__ target,
    int N, int M,
    const Prep* __restrict__ pp,
    unsigned* __restrict__ wctr, unsigned* __restrict__ dctr,
    double* __restrict__ acc, float* __restrict__ out)
{
    __shared__ __align__(16) float2 tbxy[256];
    __shared__ __align__(16) float  tb0[256];
    __shared__ int sh_t;
    __shared__ double wredd[4];

    const int tid = threadIdx.x;
    const Prep p = *pp;
    const float2* base2   = (const float2*)base;
    const float2* target2 = (const float2*)target;

    const double wNN = 1.0 / ((double)N * (double)N);
    const double wMM = 1.0 / ((double)M * (double)M);
    const double wNM = -2.0 / ((double)N * (double)M);

    double result = 0.0;

    for (;;) {
        __syncthreads();                 // prior tile's readers done (tb, sh_t)
        if (tid == 0) sh_t = (int)atomicAdd(wctr, 1u);
        __syncthreads();
        const int t = sh_t;
        if (t >= NT_TOT) break;

        // ---- decode tile ----
        int ib, jb, term;
        bool diag;
        const float2* A2;
        const float2* B2;
        double wt;                        // weight for the plain path
        float shx = 0.f, shy = 0.f;
        if (t < NT_CROSS) {
            ib = t >> 5; jb = t & 31;
            A2 = base2; B2 = target2;
            wt = wNM; diag = false; term = 2;
            shx = p.sh0; shy = p.sh1;
        } else {
            const int u = t - NT_CROSS;
            term = (u >= 1056) ? 1 : 0;
            const int v = u - term * 1056;
            // largest q with cum(q) = 65q - q^2 <= v, q in [0,31]
            int q = (int)((65.0f - sqrtf(4225.0f - 4.0f * (float)v)) * 0.5f);
            q = min(max(q, 0), 31);
            while (q > 0 && (65 * q - q * q) > v) --q;
            while (q < 31 && (65 * (q + 1) - (q + 1) * (q + 1)) <= v) ++q;
            const int r = v - (65 * q - q * q);
            const int cnt = 32 - q;
            ib = 2 * q + (r >= cnt ? 1 : 0);
            jb = q + (r >= cnt ? r - cnt : r);
            diag = (jb == q);
            A2 = term ? target2 : base2;  B2 = A2;
            wt = 2.0 * (term ? wMM : wNN);
        }
        const int i0 = ib * 128, j0 = jb * 256;

        // ---- stage B columns (scaled, no shift) ----
        {
            float2 b = B2[j0 + tid];
            float bx = b.x * p.f0, by = b.y * p.f1;
            tbxy[tid] = make_float2(bx, by);
            tb0[tid]  = -fmaf(bx, bx, by * by);
        }
        __syncthreads();

        // ---- per-thread row ----
        const int row = i0 + (tid & 127);
        const int js  = (tid >> 7) * 128;
        float2 a = A2[row];
        const float ax = fmaf(a.x, p.f0, -shx);
        const float ay = fmaf(a.y, p.f1, -shy);
        const float ax2 = ax + ax, ay2 = ay + ay;
        const float A0 = -fmaf(ax, ax, ay * ay);
        const float4* bp = (const float4*)(tbxy + js);
        const float4* cp = (const float4*)(tb0 + js);

        if (!diag) {
            float s0 = 0.f, s1 = 0.f, s2 = 0.f, s3 = 0.f;
#pragma unroll 4
            for (int q = 0; q < 32; ++q) {
                float4 pA = bp[2 * q];
                float4 pB = bp[2 * q + 1];
                float4 c  = cp[q];
                float e0 = fmaf(ax2, pA.x, c.x) + fmaf(ay2, pA.y, A0);
                float e1 = fmaf(ax2, pA.z, c.y) + fmaf(ay2, pA.w, A0);
                float e2 = fmaf(ax2, pB.x, c.z) + fmaf(ay2, pB.y, A0);
                float e3 = fmaf(ax2, pB.z, c.w) + fmaf(ay2, pB.w, A0);
                float m = fmaxf(fmaxf(e0, e1), fmaxf(e2, e3));
                if (__any(m > SKIP_CUT)) {
                    s0 += fexp2(e0); s1 += fexp2(e1);
                    s2 += fexp2(e2); s3 += fexp2(e3);
                }
            }
            result += wt * (double)((s0 + s1) + (s2 + s3));
        } else {
            // weight 2 for col>row, 1 for col==row, 0 for col<row (= sge+sgt)
            float sge = 0.f, sgt = 0.f;
            const int jbase = j0 + js;
#pragma unroll 2
            for (int q = 0; q < 32; ++q) {
                float4 pA = bp[2 * q];
                float4 pB = bp[2 * q + 1];
                float4 c  = cp[q];
                float e0 = fmaf(ax2, pA.x, c.x) + fmaf(ay2, pA.y, A0);
                float e1 = fmaf(ax2, pA.z, c.y) + fmaf(ay2, pA.w, A0);
                float e2 = fmaf(ax2, pB.x, c.z) + fmaf(ay2, pB.y, A0);
                float e3 = fmaf(ax2, pB.z, c.w) + fmaf(ay2, pB.w, A0);
                float v0 = fexp2(e0), v1 = fexp2(e1);
                float v2 = fexp2(e2), v3 = fexp2(e3);
                const int j = jbase + 4 * q;
                sge += (j + 0 >= row) ? v0 : 0.f;  sgt += (j + 0 > row) ? v0 : 0.f;
                sge += (j + 1 >= row) ? v1 : 0.f;  sgt += (j + 1 > row) ? v1 : 0.f;
                sge += (j + 2 >= row) ? v2 : 0.f;  sgt += (j + 2 > row) ? v2 : 0.f;
                sge += (j + 3 >= row) ? v3 : 0.f;  sgt += (j + 3 > row) ? v3 : 0.f;
            }
            result += (term ? wMM : wNN) * (double)(sge + sgt);
        }
    }

    // ---- block reduce, publish, last block writes out ----
    for (int off = 32; off; off >>= 1) result += __shfl_down(result, off);
    if ((tid & 63) == 0) wredd[tid >> 6] = result;
    __syncthreads();
    if (tid == 0) {
        double s = wredd[0] + wredd[1] + wredd[2] + wredd[3];
        atomicAdd(acc, s);
        __threadfence();
        unsigned d = atomicAdd(dctr, 1u);
        if (d == (unsigned)(gridDim.x - 1)) {
            double tot = atomicAdd(acc, 0.0);   // atomic read of final sum
            out[0] = (float)tot;
        }
    }
}

extern "C" void kernel_launch(void* const* d_in, const int* in_sizes, int n_in,
                              void* d_out, int out_size, void* d_ws, size_t ws_size,
                              hipStream_t stream)
{
    const float* base      = (const float*)d_in[0];
    const float* target    = (const float*)d_in[1];
    const float* log_sigma = (const float*)d_in[2];
    const float* log_scale = (const float*)d_in[3];
    float* out = (float*)d_out;

    int N = in_sizes[0] / 2;
    int M = in_sizes[1] / 2;

    Prep*     pp   = (Prep*)d_ws;                         // 16 B
    unsigned* wctr = (unsigned*)((char*)d_ws + 16);
    unsigned* dctr = (unsigned*)((char*)d_ws + 20);
    double*   acc  = (double*)((char*)d_ws + 32);

    prep_kernel<<<1, 1024, 0, stream>>>(base, target, log_sigma, log_scale,
                                        N, M, pp, wctr, dctr, acc);
    mmd_main<<<GRID, BLOCK, 0, stream>>>(base, target, N, M,
                                         pp, wctr, dctr, acc, out);
}

// Round 6
// 91.810 us; speedup vs baseline: 2.0333x; 2.0333x over previous
//
#include <hip/hip_runtime.h>

// Gaussian-kernel MMD loss, N=M=8192, D=2 — 3 plain launches:
//   prep (means/constants) -> main (4160 static tiles) -> final (reduce 64).
// loss = mean(k_bb) + mean(k_tt) - 2*mean(k_bt), k = exp(-||x-y||^2/(2 s^2))
// - Centering affects only the cross term: shift folded into A (base) side.
// - Coords pre-scaled by exp(log_scale)*sqrt(inv2s2*log2e); dot-form exponent
//   e = 2ax*bx + 2ay*by - |a|^2 - |b|^2 (= -d^2 scaled); k = exp2(e).
// - Tiles 128 rows x 256 cols, all equal cost: cross 64x32=2048; per sym term
//   1056 upper-triangle (off-diag weight 2, diagonal-band per-pair masked).
// - SoA LDS (bx, by, c) + float2 ext-vector math -> v_pk_fma_f32.
// - Block partials -> 64 spread f64 atomic slots (off critical path).

#define BLOCK 256
#define NT_CROSS 2048
#define NT_TOT   4160
#define LOG2E 1.4426950408889634f

typedef float v2f __attribute__((ext_vector_type(2)));

struct Prep { float f0, f1, sh0, sh1; };

__device__ __forceinline__ float fexp2(float x) {
    return __builtin_amdgcn_exp2f(x);
}

// ---------------- prep: means, constants, zero slots ----------------
__global__ __launch_bounds__(1024) void prep_kernel(
    const float* __restrict__ base, const float* __restrict__ target,
    const float* __restrict__ log_sigma, const float* __restrict__ log_scale,
    int N, int M, Prep* __restrict__ pp, double* __restrict__ slots)
{
    __shared__ double mred[16][4];
    const int tid = threadIdx.x;
    if (tid < 64) slots[tid] = 0.0;

    double sbx = 0, sby = 0, stx = 0, sty = 0;
    const float4* b4 = (const float4*)base;
    const float4* t4 = (const float4*)target;
    for (int i = tid; i < (N >> 1); i += 1024) {
        float4 v = b4[i];
        sbx += (double)v.x + (double)v.z;
        sby += (double)v.y + (double)v.w;
    }
    for (int i = tid; i < (M >> 1); i += 1024) {
        float4 v = t4[i];
        stx += (double)v.x + (double)v.z;
        sty += (double)v.y + (double)v.w;
    }
    for (int off = 32; off; off >>= 1) {
        sbx += __shfl_down(sbx, off); sby += __shfl_down(sby, off);
        stx += __shfl_down(stx, off); sty += __shfl_down(sty, off);
    }
    if ((tid & 63) == 0) {
        mred[tid >> 6][0] = sbx; mred[tid >> 6][1] = sby;
        mred[tid >> 6][2] = stx; mred[tid >> 6][3] = sty;
    }
    __syncthreads();
    if (tid == 0) {
        double b0 = 0, b1 = 0, t0 = 0, t1 = 0;
        for (int k = 0; k < 16; ++k) {
            b0 += mred[k][0]; b1 += mred[k][1];
            t0 += mred[k][2]; t1 += mred[k][3];
        }
        float s0 = expf(log_scale[0]);
        float s1 = expf(log_scale[1]);
        float sigma = expf(log_sigma[0]);
        float inv2s2 = 1.0f / (2.0f * sigma * sigma);
        float sq = sqrtf(inv2s2 * LOG2E);
        float f0 = s0 * sq, f1 = s1 * sq;
        pp->f0 = f0; pp->f1 = f1;
        pp->sh0 = (float)(b0 / (double)N - t0 / (double)M) * f0;
        pp->sh1 = (float)(b1 / (double)N - t1 / (double)M) * f1;
    }
}

// ---------------- main: 4160 static 128x256 tiles ----------------
__global__ __launch_bounds__(BLOCK, 8) void mmd_main(
    const float* __restrict__ base, const float* __restrict__ target,
    int N, int M, const Prep* __restrict__ pp, double* __restrict__ slots)
{
    __shared__ __align__(16) float tbx[256];
    __shared__ __align__(16) float tby[256];
    __shared__ __align__(16) float tbc[256];
    __shared__ double wredd[4];

    const int tid = threadIdx.x;
    const int t   = blockIdx.x;
    const Prep p = *pp;
    const float2* base2   = (const float2*)base;
    const float2* target2 = (const float2*)target;

    const double wNN = 1.0 / ((double)N * (double)N);
    const double wMM = 1.0 / ((double)M * (double)M);
    const double wNM = -2.0 / ((double)N * (double)M);

    // ---- decode tile ----
    int ib, jb;
    bool diag;
    int term;
    const float2* A2;
    const float2* B2;
    double wt;
    float shx = 0.f, shy = 0.f;
    if (t < NT_CROSS) {
        ib = t >> 5; jb = t & 31;
        A2 = base2; B2 = target2;
        wt = wNM; diag = false; term = 2;
        shx = p.sh0; shy = p.sh1;
    } else {
        const int u = t - NT_CROSS;
        term = (u >= 1056) ? 1 : 0;
        const int v = u - term * 1056;
        int q = (int)((65.0f - sqrtf(4225.0f - 4.0f * (float)v)) * 0.5f);
        q = min(max(q, 0), 31);
        while (q > 0 && (65 * q - q * q) > v) --q;
        while (q < 31 && (65 * (q + 1) - (q + 1) * (q + 1)) <= v) ++q;
        const int r = v - (65 * q - q * q);
        const int cnt = 32 - q;
        ib = 2 * q + (r >= cnt ? 1 : 0);
        jb = q + (r >= cnt ? r - cnt : r);
        diag = (jb == q);
        A2 = term ? target2 : base2;  B2 = A2;
        wt = 2.0 * (term ? wMM : wNN);
    }
    const int i0 = ib * 128, j0 = jb * 256;

    // ---- stage B columns (SoA, scaled) ----
    {
        float2 b = B2[j0 + tid];
        float bx = b.x * p.f0, by = b.y * p.f1;
        tbx[tid] = bx;
        tby[tid] = by;
        tbc[tid] = -fmaf(bx, bx, by * by);
    }
    __syncthreads();

    // ---- per-thread row ----
    const int row = i0 + (tid & 127);
    const int js  = (tid >> 7) * 128;
    float2 a = A2[row];
    const float ax = fmaf(a.x, p.f0, -shx);
    const float ay = fmaf(a.y, p.f1, -shy);
    const float ax2 = ax + ax, ay2 = ay + ay;
    const float A0 = -fmaf(ax, ax, ay * ay);

    const float4* bx4 = (const float4*)(tbx + js);
    const float4* by4 = (const float4*)(tby + js);
    const float4* c4  = (const float4*)(tbc + js);

    double result;
    if (!diag) {
        const v2f ax2v = { ax2, ax2 };
        const v2f ay2v = { ay2, ay2 };
        const v2f A0v  = { A0, A0 };
        v2f s01 = { 0.f, 0.f }, s23 = { 0.f, 0.f };
#pragma unroll 4
        for (int q = 0; q < 32; ++q) {
            float4 BX = bx4[q];
            float4 BY = by4[q];
            float4 C  = c4[q];
            v2f bx01 = { BX.x, BX.y }, bx23 = { BX.z, BX.w };
            v2f by01 = { BY.x, BY.y }, by23 = { BY.z, BY.w };
            v2f c01  = { C.x,  C.y  }, c23  = { C.z,  C.w  };
            v2f e01 = ax2v * bx01 + (ay2v * by01 + (c01 + A0v));
            v2f e23 = ax2v * bx23 + (ay2v * by23 + (c23 + A0v));
            v2f x01 = { fexp2(e01.x), fexp2(e01.y) };
            v2f x23 = { fexp2(e23.x), fexp2(e23.y) };
            s01 += x01;
            s23 += x23;
        }
        v2f st = s01 + s23;
        result = wt * (double)(st.x + st.y);
    } else {
        // weight 2 for col>row, 1 for col==row, 0 for col<row  (= sge + sgt)
        float sge = 0.f, sgt = 0.f;
        const int jbase = j0 + js;
#pragma unroll 2
        for (int q = 0; q < 32; ++q) {
            float4 BX = bx4[q];
            float4 BY = by4[q];
            float4 C  = c4[q];
            float e0 = fmaf(ax2, BX.x, fmaf(ay2, BY.x, C.x + A0));
            float e1 = fmaf(ax2, BX.y, fmaf(ay2, BY.y, C.y + A0));
            float e2 = fmaf(ax2, BX.z, fmaf(ay2, BY.z, C.z + A0));
            float e3 = fmaf(ax2, BX.w, fmaf(ay2, BY.w, C.w + A0));
            float v0 = fexp2(e0), v1 = fexp2(e1);
            float v2 = fexp2(e2), v3 = fexp2(e3);
            const int j = jbase + 4 * q;
            sge += (j + 0 >= row) ? v0 : 0.f;  sgt += (j + 0 > row) ? v0 : 0.f;
            sge += (j + 1 >= row) ? v1 : 0.f;  sgt += (j + 1 > row) ? v1 : 0.f;
            sge += (j + 2 >= row) ? v2 : 0.f;  sgt += (j + 2 > row) ? v2 : 0.f;
            sge += (j + 3 >= row) ? v3 : 0.f;  sgt += (j + 3 > row) ? v3 : 0.f;
        }
        result = (term ? wMM : wNN) * (double)(sge + sgt);
    }

    // ---- block reduce (f64), publish to spread slots ----
    for (int off = 32; off; off >>= 1) result += __shfl_down(result, off);
    if ((tid & 63) == 0) wredd[tid >> 6] = result;
    __syncthreads();
    if (tid == 0) {
        double s = wredd[0] + wredd[1] + wredd[2] + wredd[3];
        atomicAdd(&slots[t & 63], s);
    }
}

// ---------------- final: reduce 64 slots ----------------
__global__ void final_kernel(const double* __restrict__ slots,
                             float* __restrict__ out)
{
    const int tid = threadIdx.x;
    double s = slots[tid];
    for (int off = 32; off; off >>= 1) s += __shfl_down(s, off);
    if (tid == 0) out[0] = (float)s;
}

extern "C" void kernel_launch(void* const* d_in, const int* in_sizes, int n_in,
                              void* d_out, int out_size, void* d_ws, size_t ws_size,
                              hipStream_t stream)
{
    const float* base      = (const float*)d_in[0];
    const float* target    = (const float*)d_in[1];
    const float* log_sigma = (const float*)d_in[2];
    const float* log_scale = (const float*)d_in[3];
    float* out = (float*)d_out;

    int N = in_sizes[0] / 2;
    int M = in_sizes[1] / 2;

    Prep*   pp    = (Prep*)d_ws;                       // 16 B
    double* slots = (double*)((char*)d_ws + 64);       // 64 doubles

    prep_kernel<<<1, 1024, 0, stream>>>(base, target, log_sigma, log_scale,
                                        N, M, pp, slots);
    mmd_main<<<NT_TOT, BLOCK, 0, stream>>>(base, target, N, M, pp, slots);
    final_kernel<<<1, 64, 0, stream>>>(slots, out);
}